// Round 1
// baseline (275.724 us; speedup 1.0000x reference)
//
#include <hip/hip_runtime.h>
#include <hip/hip_bf16.h>
#include <stdint.h>

#define DEV __device__ __forceinline__

typedef __attribute__((ext_vector_type(8))) short bf16x8;
typedef __attribute__((ext_vector_type(4))) float f32x4;
typedef __attribute__((ext_vector_type(16))) float f32x16;
typedef unsigned short u16;

// ---- async global->LDS, 16B per lane. lds dest must be wave-uniform base. ----
DEV void gload_lds16(const void* g, void* l) {
    typedef const __attribute__((address_space(1))) unsigned int* gp_t;
    typedef __attribute__((address_space(3))) unsigned int* lp_t;
    __builtin_amdgcn_global_load_lds((gp_t)(uintptr_t)g, (lp_t)(uint32_t)(uintptr_t)l, 16, 0, 0);
}

DEV u16 f2bf(float x) {
    union { __hip_bfloat16 h; u16 u; } c;
    c.h = __float2bfloat16(x);
    return c.u;
}
DEV unsigned pack2bf(float a, float b) {
    return (unsigned)f2bf(a) | ((unsigned)f2bf(b) << 16);
}

// ============================ cast fp32 -> bf16 ============================
__global__ void cast_kernel(const float* __restrict__ src, u16* __restrict__ dst, int n8) {
    int stride = gridDim.x * blockDim.x;
    for (int i = blockIdx.x * blockDim.x + threadIdx.x; i < n8; i += stride) {
        const float4* s = (const float4*)src + (size_t)i * 2;
        float4 a = s[0], b = s[1];
        union { u16 u[8]; uint4 v; } o;
        o.u[0] = f2bf(a.x); o.u[1] = f2bf(a.y); o.u[2] = f2bf(a.z); o.u[3] = f2bf(a.w);
        o.u[4] = f2bf(b.x); o.u[5] = f2bf(b.y); o.u[6] = f2bf(b.z); o.u[7] = f2bf(b.w);
        *((uint4*)dst + i) = o.v;
    }
}

// ============================ projection GEMM ==============================
// out[m][n] = sum_k A[m][k]*Bw[n][k] + bias   (A,Bw row-major, K=256 fixed)
// 128x128 tile, BK=64, 4 waves each 64x64 via 4x4 of 16x16x32 MFMA.
DEV void gemm_body(const u16* A, const u16* Bw, const float* bias, int bias_row,
                   u16* out, int out_pitch)
{
    __shared__ char smA[16384];
    __shared__ char smB[16384];
    const int lane = threadIdx.x & 63;
    const int w    = threadIdx.x >> 6;
    const int wr   = w >> 1, wc = w & 1;
    const int l15  = lane & 15, lg = lane >> 4;

    f32x4 acc[4][4] = {};
    const char* ag = (const char*)A;
    const char* bg = (const char*)Bw;

    for (int kt = 0; kt < 4; ++kt) {
        __syncthreads();
        // stage A (chunks 0..15) and B (16..31); wave-uniform lds base, pre-swizzled src
        #pragma unroll
        for (int c = 0; c < 8; ++c) {
            int ch    = w * 8 + c;
            int loc   = ch & 15;
            int p     = loc * 1024 + lane * 16;
            int row   = p >> 7;                       // 0..127
            int inner = (p & 127) ^ ((row & 7) << 4); // both-sides XOR swizzle
            const char* src = (ch < 16 ? ag : bg) + row * 512 + kt * 128 + inner;
            char* dst = (ch < 16 ? smA : smB) + loc * 1024;
            gload_lds16(src, dst);
        }
        __syncthreads();
        #pragma unroll
        for (int ks = 0; ks < 2; ++ks) {
            bf16x8 af[4], bfr[4];
            #pragma unroll
            for (int mi = 0; mi < 4; ++mi) {
                int row = wr * 64 + mi * 16 + l15;
                af[mi] = *(const bf16x8*)(smA + ((row * 128 + ks * 64 + lg * 16) ^ ((row & 7) << 4)));
            }
            #pragma unroll
            for (int ni = 0; ni < 4; ++ni) {
                int row = wc * 64 + ni * 16 + l15;
                bfr[ni] = *(const bf16x8*)(smB + ((row * 128 + ks * 64 + lg * 16) ^ ((row & 7) << 4)));
            }
            #pragma unroll
            for (int mi = 0; mi < 4; ++mi)
                #pragma unroll
                for (int ni = 0; ni < 4; ++ni)
                    acc[mi][ni] = __builtin_amdgcn_mfma_f32_16x16x32_bf16(af[mi], bfr[ni], acc[mi][ni], 0, 0, 0);
        }
    }
    // epilogue: C/D layout col=lane&15, row=(lane>>4)*4+r
    #pragma unroll
    for (int mi = 0; mi < 4; ++mi) {
        #pragma unroll
        for (int ni = 0; ni < 4; ++ni) {
            int n_l  = wc * 64 + ni * 16 + l15;
            float bn = bias_row ? 0.f : bias[n_l];
            #pragma unroll
            for (int r = 0; r < 4; ++r) {
                int row  = wr * 64 + mi * 16 + lg * 4 + r;
                float bb = bias_row ? bias[row] : bn;
                out[(size_t)row * out_pitch + n_l] = f2bf(acc[mi][ni][r] + bb);
            }
        }
    }
}

__global__ __launch_bounds__(256) void proj_qk_kernel(
    const u16* xb, const u16* wqb, const u16* wkb,
    const float* bq, const float* bk, u16* Q, u16* K)
{
    int n0 = blockIdx.x * 128;   // 0..511, [0,256)=Q [256,512)=K
    int m0 = blockIdx.y * 128;
    bool isK = n0 >= 256;
    int  nl  = n0 & 255;
    gemm_body(xb + (size_t)m0 * 256, (isK ? wkb : wqb) + (size_t)nl * 256,
              (isK ? bk : bq) + nl, 0,
              (isK ? K : Q) + (size_t)m0 * 256 + nl, 256);
}

__global__ __launch_bounds__(256) void proj_v_kernel(
    const u16* wvb, const u16* xb, const float* bv, u16* Vt)
{
    int n0 = blockIdx.x * 128;   // token tile
    int m0 = blockIdx.y * 128;   // d tile (0 or 128)
    gemm_body(wvb + (size_t)m0 * 256, xb + (size_t)n0 * 256, bv + m0, 1,
              Vt + (size_t)m0 * 32768 + n0, 32768);
}

// ============================ fused attention ==============================
// Block: 4 waves, 128 q-rows (32/wave). KV tile = 64. Swapped QK^T (S^T=K*Q^T)
// so each lane owns one q-row; P goes to PV's B-operand entirely in registers.
__global__ __launch_bounds__(256, 1) void attn_kernel(
    const u16* Q, const u16* K, const u16* Vt, float* out)
{
    __shared__ char sm[65536];
    char* kls = sm;            // K tile:  [64 kv][512B], swz ^((row&31)<<4)
    char* vls = sm + 32768;    // Vt tile: [256 d][128B], swz ^((row&7)<<4)

    const int lane = threadIdx.x & 63;
    const int w    = threadIdx.x >> 6;
    const int q32  = lane & 31;
    const int g    = lane >> 5;
    const int b    = blockIdx.y;
    const size_t tokbase = (size_t)b * 2048;
    const int q0   = blockIdx.x * 128 + w * 32;

    // Q fragments (B-operand of S^T): lane holds Q[q0+q32][ks*16 + g*8 + j]
    bf16x8 qf[16];
    {
        const char* qrow = (const char*)(Q + (tokbase + q0 + q32) * 256);
        #pragma unroll
        for (int ks = 0; ks < 16; ++ks)
            qf[ks] = *(const bf16x8*)(qrow + ks * 32 + g * 16);
    }

    f32x16 acc[8] = {};            // O^T tiles: acc[dt], d = dt*32+..., q = lane&31
    float m_run = -1e30f;
    float l_run = 0.f;
    const float C = 0.09016844005556021f;   // (1/16)*log2(e)

    for (int kt = 0; kt < 32; ++kt) {
        const int kv0 = kt * 64;
        __syncthreads();
        if (w < 2) {               // waves 0,1 stage K tile (32KB)
            #pragma unroll
            for (int c = 0; c < 16; ++c) {
                int chunk = w * 16 + c;
                int p     = chunk * 1024 + lane * 16;
                int row   = p >> 9;
                int inner = (p & 511) ^ ((row & 31) << 4);
                const char* src = (const char*)K + (tokbase + kv0 + row) * 512 + inner;
                gload_lds16(src, kls + chunk * 1024);
            }
        } else {                   // waves 2,3 stage Vt tile (32KB)
            #pragma unroll
            for (int c = 0; c < 16; ++c) {
                int chunk = (w - 2) * 16 + c;
                int p     = chunk * 1024 + lane * 16;
                int row   = p >> 7;                    // d: 0..255
                int inner = (p & 127) ^ ((row & 7) << 4);
                const char* src = (const char*)Vt + (size_t)row * 65536 + (tokbase + kv0) * 2 + inner;
                gload_lds16(src, vls + chunk * 1024);
            }
        }
        __syncthreads();

        // ---- S^T = K * Q^T : st[mt][reg] = S[q=lane&31][kv=mt*32+(reg&3)+8*(reg>>2)+4g]
        f32x16 st[2] = {};
        #pragma unroll
        for (int ks = 0; ks < 16; ++ks) {
            #pragma unroll
            for (int mt = 0; mt < 2; ++mt) {
                int row = mt * 32 + q32;
                bf16x8 kf = *(const bf16x8*)(kls + ((row * 512 + ks * 32 + g * 16) ^ ((row & 31) << 4)));
                st[mt] = __builtin_amdgcn_mfma_f32_32x32x16_bf16(kf, qf[ks], st[mt], 0, 0, 0);
            }
        }

        // ---- online softmax: lane pair (l, l^32) shares q-row
        float pmax = st[0][0];
        #pragma unroll
        for (int i = 1; i < 16; ++i) pmax = fmaxf(pmax, st[0][i]);
        #pragma unroll
        for (int i = 0; i < 16; ++i) pmax = fmaxf(pmax, st[1][i]);
        pmax = fmaxf(pmax, __shfl_xor(pmax, 32, 64));

        bool upd = pmax > m_run + 16.f;     // defer-max: raw-units threshold
        if (__any(upd)) {
            float m_new = upd ? pmax : m_run;
            float rs = upd ? exp2f((m_run - m_new) * C) : 1.f;
            #pragma unroll
            for (int dt = 0; dt < 8; ++dt) acc[dt] *= rs;
            l_run *= rs;
            m_run = m_new;
        }

        const float mc = m_run * C;
        float sum = 0.f;
        #pragma unroll
        for (int mt = 0; mt < 2; ++mt)
            #pragma unroll
            for (int i = 0; i < 16; ++i) {
                float e = exp2f(st[mt][i] * C - mc);
                st[mt][i] = e;
                sum += e;
            }
        sum += __shfl_xor(sum, 32, 64);
        l_run += sum;

        // ---- pack P rows to bf16 dwords: pk[mt][c][h] = kv {mt*32+8c+4g+2h, +1}
        unsigned pk[2][4][2];
        #pragma unroll
        for (int mt = 0; mt < 2; ++mt)
            #pragma unroll
            for (int c = 0; c < 4; ++c) {
                pk[mt][c][0] = pack2bf(st[mt][c * 4 + 0], st[mt][c * 4 + 1]);
                pk[mt][c][1] = pack2bf(st[mt][c * 4 + 2], st[mt][c * 4 + 3]);
            }

        // ---- PV: acc[dt] += Vt_tile(dt) * P^T. B-frag built in-register.
        #pragma unroll
        for (int ks = 0; ks < 4; ++ks) {
            const int mt = ks >> 1;
            const int k1 = ks & 1;
            unsigned a0 = g ? pk[mt][2 * k1 + 1][0] : pk[mt][2 * k1][0];
            unsigned a1 = g ? pk[mt][2 * k1 + 1][1] : pk[mt][2 * k1][1];
            unsigned s0 = g ? pk[mt][2 * k1][0]     : pk[mt][2 * k1 + 1][0];
            unsigned s1 = g ? pk[mt][2 * k1][1]     : pk[mt][2 * k1 + 1][1];
            unsigned p0 = __shfl_xor(s0, 32, 64);
            unsigned p1 = __shfl_xor(s1, 32, 64);
            union { unsigned u[4]; bf16x8 v; } pf;
            pf.u[0] = g ? p0 : a0;
            pf.u[1] = g ? p1 : a1;
            pf.u[2] = g ? a0 : p0;
            pf.u[3] = g ? a1 : p1;
            #pragma unroll
            for (int dt = 0; dt < 8; ++dt) {
                int row = dt * 32 + q32;
                bf16x8 vf = *(const bf16x8*)(vls + ((row * 128 + ks * 32 + g * 16) ^ ((row & 7) << 4)));
                acc[dt] = __builtin_amdgcn_mfma_f32_32x32x16_bf16(vf, pf.v, acc[dt], 0, 0, 0);
            }
        }
    }

    // ---- epilogue: O = acc / l, transpose via LDS for coalesced fp32 stores
    __syncthreads();
    const float inv = 1.f / l_run;
    float* ow = (float*)(sm + w * 8448);   // per-wave [32 q][66 d-chunk] f32
    #pragma unroll
    for (int p = 0; p < 4; ++p) {          // 64-wide d chunks
        #pragma unroll
        for (int dt2 = 0; dt2 < 2; ++dt2) {
            const int dt = p * 2 + dt2;
            #pragma unroll
            for (int r = 0; r < 16; ++r) {
                int dl = dt2 * 32 + (r & 3) + 8 * (r >> 2) + 4 * g;
                ow[q32 * 66 + dl] = acc[dt][r] * inv;
            }
        }
        #pragma unroll
        for (int it = 0; it < 8; ++it) {
            int qr = it * 4 + (lane >> 4);
            int dc = (lane & 15) * 4;
            float2 lo = *(const float2*)(ow + qr * 66 + dc);
            float2 hi = *(const float2*)(ow + qr * 66 + dc + 2);
            float4 v;
            v.x = lo.x; v.y = lo.y; v.z = hi.x; v.w = hi.y;
            *(float4*)(out + (tokbase + q0 + qr) * 256 + p * 64 + dc) = v;
        }
    }
}

// ================================ launch ===================================
extern "C" void kernel_launch(void* const* d_in, const int* in_sizes, int n_in,
                              void* d_out, int out_size, void* d_ws, size_t ws_size,
                              hipStream_t stream) {
    (void)in_sizes; (void)n_in; (void)out_size; (void)ws_size;
    const float* x  = (const float*)d_in[0];
    const float* Wq = (const float*)d_in[1];
    const float* bq = (const float*)d_in[2];
    const float* Wk = (const float*)d_in[3];
    const float* bk = (const float*)d_in[4];
    const float* Wv = (const float*)d_in[5];
    const float* bv = (const float*)d_in[6];
    float* out = (float*)d_out;

    char* ws = (char*)d_ws;
    u16* xb  = (u16*)(ws);                  // 16,777,216 B
    u16* wqb = (u16*)(ws + 16777216);       //    131,072
    u16* wkb = (u16*)(ws + 16908288);       //    131,072
    u16* wvb = (u16*)(ws + 17039360);       //    131,072
    u16* Qb  = (u16*)(ws + 17170432);       // 16,777,216
    u16* Kb  = (u16*)(ws + 33947648);       // 16,777,216
    u16* Vtb = (u16*)(ws + 50724864);       // 16,777,216  (total ~64.4 MB)

    cast_kernel<<<2048, 256, 0, stream>>>(x,  xb,  1048576);
    cast_kernel<<<64,   256, 0, stream>>>(Wq, wqb, 8192);
    cast_kernel<<<64,   256, 0, stream>>>(Wk, wkb, 8192);
    cast_kernel<<<64,   256, 0, stream>>>(Wv, wvb, 8192);

    proj_qk_kernel<<<dim3(4, 256), 256, 0, stream>>>(xb, wqb, wkb, bq, bk, Qb, Kb);
    proj_v_kernel<<<dim3(256, 2), 256, 0, stream>>>(wvb, xb, bv, Vtb);

    attn_kernel<<<dim3(16, 16), 256, 0, stream>>>(Qb, Kb, Vtb, out);
}

// Round 3
// 196.597 us; speedup vs baseline: 1.4025x; 1.4025x over previous
//
#include <hip/hip_runtime.h>
#include <hip/hip_bf16.h>
#include <stdint.h>

#define DEV __device__ __forceinline__

typedef __attribute__((ext_vector_type(8))) short bf16x8;
typedef __attribute__((ext_vector_type(4))) float f32x4;
typedef __attribute__((ext_vector_type(16))) float f32x16;
typedef unsigned short u16;

// ---- async global->LDS, 16B per lane. lds dest must be wave-uniform base. ----
DEV void gload_lds16(const void* g, void* l) {
    typedef const __attribute__((address_space(1))) unsigned int* gp_t;
    typedef __attribute__((address_space(3))) unsigned int* lp_t;
    __builtin_amdgcn_global_load_lds((gp_t)(uintptr_t)g, (lp_t)(uint32_t)(uintptr_t)l, 16, 0, 0);
}

DEV u16 f2bf(float x) {
    union { __hip_bfloat16 h; u16 u; } c;
    c.h = __float2bfloat16(x);
    return c.u;
}
DEV unsigned pack2bf(float a, float b) {
    return (unsigned)f2bf(a) | ((unsigned)f2bf(b) << 16);
}

// ============================ cast fp32 -> bf16 ============================
__global__ void cast_kernel(const float* __restrict__ src, u16* __restrict__ dst, int n8) {
    int stride = gridDim.x * blockDim.x;
    for (int i = blockIdx.x * blockDim.x + threadIdx.x; i < n8; i += stride) {
        const float4* s = (const float4*)src + (size_t)i * 2;
        float4 a = s[0], b = s[1];
        union { u16 u[8]; uint4 v; } o;
        o.u[0] = f2bf(a.x); o.u[1] = f2bf(a.y); o.u[2] = f2bf(a.z); o.u[3] = f2bf(a.w);
        o.u[4] = f2bf(b.x); o.u[5] = f2bf(b.y); o.u[6] = f2bf(b.z); o.u[7] = f2bf(b.w);
        *((uint4*)dst + i) = o.v;
    }
}

// ============================ projection GEMM ==============================
DEV void gemm_body(const u16* A, const u16* Bw, const float* bias, int bias_row,
                   u16* out, int out_pitch)
{
    __shared__ char smA[16384];
    __shared__ char smB[16384];
    const int lane = threadIdx.x & 63;
    const int w    = threadIdx.x >> 6;
    const int wr   = w >> 1, wc = w & 1;
    const int l15  = lane & 15, lg = lane >> 4;

    f32x4 acc[4][4] = {};
    const char* ag = (const char*)A;
    const char* bg = (const char*)Bw;

    for (int kt = 0; kt < 4; ++kt) {
        __syncthreads();
        #pragma unroll
        for (int c = 0; c < 8; ++c) {
            int ch    = w * 8 + c;
            int loc   = ch & 15;
            int p     = loc * 1024 + lane * 16;
            int row   = p >> 7;
            int inner = (p & 127) ^ ((row & 7) << 4);
            const char* src = (ch < 16 ? ag : bg) + row * 512 + kt * 128 + inner;
            char* dst = (ch < 16 ? smA : smB) + loc * 1024;
            gload_lds16(src, dst);
        }
        __syncthreads();
        #pragma unroll
        for (int ks = 0; ks < 2; ++ks) {
            bf16x8 af[4], bfr[4];
            #pragma unroll
            for (int mi = 0; mi < 4; ++mi) {
                int row = wr * 64 + mi * 16 + l15;
                af[mi] = *(const bf16x8*)(smA + ((row * 128 + ks * 64 + lg * 16) ^ ((row & 7) << 4)));
            }
            #pragma unroll
            for (int ni = 0; ni < 4; ++ni) {
                int row = wc * 64 + ni * 16 + l15;
                bfr[ni] = *(const bf16x8*)(smB + ((row * 128 + ks * 64 + lg * 16) ^ ((row & 7) << 4)));
            }
            #pragma unroll
            for (int mi = 0; mi < 4; ++mi)
                #pragma unroll
                for (int ni = 0; ni < 4; ++ni)
                    acc[mi][ni] = __builtin_amdgcn_mfma_f32_16x16x32_bf16(af[mi], bfr[ni], acc[mi][ni], 0, 0, 0);
        }
    }
    #pragma unroll
    for (int mi = 0; mi < 4; ++mi) {
        #pragma unroll
        for (int ni = 0; ni < 4; ++ni) {
            int n_l  = wc * 64 + ni * 16 + l15;
            float bn = bias_row ? 0.f : bias[n_l];
            #pragma unroll
            for (int r = 0; r < 4; ++r) {
                int row  = wr * 64 + mi * 16 + lg * 4 + r;
                float bb = bias_row ? bias[row] : bn;
                out[(size_t)row * out_pitch + n_l] = f2bf(acc[mi][ni][r] + bb);
            }
        }
    }
}

__global__ __launch_bounds__(256) void proj_qk_kernel(
    const u16* xb, const u16* wqb, const u16* wkb,
    const float* bq, const float* bk, u16* Q, u16* K)
{
    int n0 = blockIdx.x * 128;
    int m0 = blockIdx.y * 128;
    bool isK = n0 >= 256;
    int  nl  = n0 & 255;
    gemm_body(xb + (size_t)m0 * 256, (isK ? wkb : wqb) + (size_t)nl * 256,
              (isK ? bk : bq) + nl, 0,
              (isK ? K : Q) + (size_t)m0 * 256 + nl, 256);
}

__global__ __launch_bounds__(256) void proj_v_kernel(
    const u16* wvb, const u16* xb, const float* bv, u16* Vt)
{
    int n0 = blockIdx.x * 128;
    int m0 = blockIdx.y * 128;
    gemm_body(wvb + (size_t)m0 * 256, xb + (size_t)n0 * 256, bv + m0, 1,
              Vt + (size_t)m0 * 32768 + n0, 32768);
}

// ============================ fused attention ==============================
// 4 waves, 128 q-rows (32/wave). KVBLK=32, K+V double-buffered (4x16KB LDS).
// Schedule per tile: stage(next) -> compute(cur) -> __syncthreads().
// The syncthreads vmcnt(0) drain happens AFTER compute, so next-tile loads get
// the whole compute phase in flight (m99-style dbuf, fully compiler-fenced).
__global__ __launch_bounds__(256, 1) void attn_kernel(
    const u16* __restrict__ Q, const u16* __restrict__ K,
    const u16* __restrict__ Vt, float* __restrict__ out)
{
    __shared__ char sm[65536];
    // buffers: K tile t -> sm + (t&1)*16384        [32 kv][512B] swz ^((row&31)<<4)
    //          V tile t -> sm + 32768 + (t&1)*16384 [256 d][64B]  swz ^(((row>>1)&3)<<4)

    const int lane = threadIdx.x & 63;
    const int w    = threadIdx.x >> 6;
    const int q32  = lane & 31;
    const int g    = lane >> 5;

    // XCD batch-confinement: each XCD (lin%8) serves 2 batches -> K/V (4MB) L2-resident
    const int lin = blockIdx.y * 16 + blockIdx.x;
    const int b   = (lin & 7) * 2 + ((lin >> 3) & 1);
    const int qt  = lin >> 4;
    const size_t tokbase = (size_t)b * 2048;
    const int q0  = qt * 128 + w * 32;

    // Q fragments (B-operand of S^T): lane holds Q[q0+q32][ks*16 + g*8 + j]
    bf16x8 qf[16];
    {
        const char* qrow = (const char*)(Q + (tokbase + q0 + q32) * 256);
        #pragma unroll
        for (int ks = 0; ks < 16; ++ks)
            qf[ks] = *(const bf16x8*)(qrow + ks * 32 + g * 16);
    }

    // staging: waves 0,1 load K tile (16 chunks), waves 2,3 load V tile (16 chunks)
    auto stage = [&](int t) {
        const int kv0 = t * 32;
        char* kb = sm + ((t & 1) << 14);
        char* vb = sm + 32768 + ((t & 1) << 14);
        if (w < 2) {
            #pragma unroll
            for (int c = 0; c < 8; ++c) {
                int ch    = w * 8 + c;
                int row   = ch * 2 + (lane >> 5);
                int inner = ((lane & 31) * 16) ^ ((row & 31) << 4);
                gload_lds16((const char*)K + (tokbase + kv0 + row) * 512 + inner,
                            kb + ch * 1024);
            }
        } else {
            #pragma unroll
            for (int c = 0; c < 8; ++c) {
                int ch    = (w - 2) * 8 + c;
                int row   = ch * 16 + (lane >> 2);
                int inner = ((lane & 3) * 16) ^ (((row >> 1) & 3) << 4);
                gload_lds16((const char*)Vt + (size_t)row * 65536 + (size_t)(tokbase + kv0) * 2 + inner,
                            vb + ch * 1024);
            }
        }
    };

    f32x16 acc[8] = {};            // O^T: acc[dt], d = dt*32+crow, q = lane&31
    float m_run = -1e30f;
    float l_run = 0.f;
    const float C = 0.09016844005556021f;   // (1/16)*log2(e)

    stage(0);
    __syncthreads();               // tile 0 resident

    for (int kt = 0; kt < 64; ++kt) {
        if (kt < 63) stage(kt + 1);           // issue next-tile loads first
        const char* kls = sm + ((kt & 1) << 14);
        const char* vls = sm + 32768 + ((kt & 1) << 14);

        // ---- S^T = K * Q^T : st[r] = S[q=lane&31][kv=(r&3)+8*(r>>2)+4g]
        f32x16 st = {};
        #pragma unroll
        for (int ks = 0; ks < 16; ++ks) {
            bf16x8 kf = *(const bf16x8*)(kls + ((q32 * 512 + ks * 32 + g * 16) ^ (q32 << 4)));
            st = __builtin_amdgcn_mfma_f32_32x32x16_bf16(kf, qf[ks], st, 0, 0, 0);
        }

        // ---- online softmax (lane pair l, l^32 shares one q-row)
        float t0 = fmaxf(st[0], st[1]),   t1 = fmaxf(st[2], st[3]);
        float t2 = fmaxf(st[4], st[5]),   t3 = fmaxf(st[6], st[7]);
        float t4 = fmaxf(st[8], st[9]),   t5 = fmaxf(st[10], st[11]);
        float t6 = fmaxf(st[12], st[13]), t7 = fmaxf(st[14], st[15]);
        t0 = fmaxf(t0, t1); t2 = fmaxf(t2, t3); t4 = fmaxf(t4, t5); t6 = fmaxf(t6, t7);
        float pmax = fmaxf(fmaxf(t0, t2), fmaxf(t4, t6));
        pmax = fmaxf(pmax, __shfl_xor(pmax, 32, 64));

        bool upd = pmax > m_run + 16.f;     // defer-max (exp arg bounded by 16*C=1.44)
        if (__any(upd)) {
            float m_new = upd ? pmax : m_run;
            float rs = upd ? exp2f((m_run - m_new) * C) : 1.f;
            #pragma unroll
            for (int dt = 0; dt < 8; ++dt) acc[dt] *= rs;
            l_run *= rs;
            m_run = m_new;
        }

        const float mc = m_run * C;
        float sum = 0.f;
        #pragma unroll
        for (int i = 0; i < 16; ++i) {
            float e = exp2f(st[i] * C - mc);
            st[i] = e;
            sum += e;
        }
        sum += __shfl_xor(sum, 32, 64);
        l_run += sum;

        // ---- pack P to bf16: pk[c][h] = kv {8c+4g+2h, 8c+4g+2h+1}  (constant idx only)
        unsigned pk[4][2];
        #pragma unroll
        for (int c = 0; c < 4; ++c) {
            pk[c][0] = pack2bf(st[c * 4 + 0], st[c * 4 + 1]);
            pk[c][1] = pack2bf(st[c * 4 + 2], st[c * 4 + 3]);
        }

        // ---- PV: acc[dt] += Vt_tile(dt) * P^T (B-frag built in-register)
        #pragma unroll
        for (int ks = 0; ks < 2; ++ks) {
            unsigned a0 = g ? pk[2 * ks + 1][0] : pk[2 * ks][0];
            unsigned a1 = g ? pk[2 * ks + 1][1] : pk[2 * ks][1];
            unsigned s0 = g ? pk[2 * ks][0]     : pk[2 * ks + 1][0];
            unsigned s1 = g ? pk[2 * ks][1]     : pk[2 * ks + 1][1];
            unsigned p0 = __shfl_xor(s0, 32, 64);
            unsigned p1 = __shfl_xor(s1, 32, 64);
            union { unsigned u[4]; bf16x8 v; } pf;
            pf.u[0] = g ? p0 : a0;
            pf.u[1] = g ? p1 : a1;
            pf.u[2] = g ? a0 : p0;
            pf.u[3] = g ? a1 : p1;
            #pragma unroll
            for (int dt = 0; dt < 8; ++dt) {
                int row = dt * 32 + q32;
                bf16x8 vf = *(const bf16x8*)(vls + ((row * 64 + ks * 32 + g * 16) ^ (((row >> 1) & 3) << 4)));
                acc[dt] = __builtin_amdgcn_mfma_f32_32x32x16_bf16(vf, pf.v, acc[dt], 0, 0, 0);
            }
        }
        __syncthreads();   // drains this iter's staged loads + fences buffer reuse
    }

    // ---- epilogue: O = acc / l, transpose via LDS for coalesced fp32 stores
    // (same-wave DS ordering guarantees write->read visibility; regions per-wave)
    const float inv = 1.f / l_run;
    float* ow = (float*)(sm + w * 8448);   // per-wave [32 q][66 f32]
    #pragma unroll
    for (int p = 0; p < 4; ++p) {
        #pragma unroll
        for (int dt2 = 0; dt2 < 2; ++dt2) {
            const int dt = p * 2 + dt2;
            #pragma unroll
            for (int r = 0; r < 16; ++r) {
                int dl = dt2 * 32 + (r & 3) + 8 * (r >> 2) + 4 * g;
                ow[q32 * 66 + dl] = acc[dt][r] * inv;
            }
        }
        #pragma unroll
        for (int it = 0; it < 8; ++it) {
            int qr = it * 4 + (lane >> 4);
            int dc = (lane & 15) * 4;
            float2 lo = *(const float2*)(ow + qr * 66 + dc);
            float2 hi = *(const float2*)(ow + qr * 66 + dc + 2);
            float4 v;
            v.x = lo.x; v.y = lo.y; v.z = hi.x; v.w = hi.y;
            *(float4*)(out + (tokbase + q0 + qr) * 256 + p * 64 + dc) = v;
        }
        __syncthreads();   // keep waves' phase p regions coherent before overwrite
    }
}

// ================================ launch ===================================
extern "C" void kernel_launch(void* const* d_in, const int* in_sizes, int n_in,
                              void* d_out, int out_size, void* d_ws, size_t ws_size,
                              hipStream_t stream) {
    (void)in_sizes; (void)n_in; (void)out_size; (void)ws_size;
    const float* x  = (const float*)d_in[0];
    const float* Wq = (const float*)d_in[1];
    const float* bq = (const float*)d_in[2];
    const float* Wk = (const float*)d_in[3];
    const float* bk = (const float*)d_in[4];
    const float* Wv = (const float*)d_in[5];
    const float* bv = (const float*)d_in[6];
    float* out = (float*)d_out;

    char* ws = (char*)d_ws;
    u16* xb  = (u16*)(ws);
    u16* wqb = (u16*)(ws + 16777216);
    u16* wkb = (u16*)(ws + 16908288);
    u16* wvb = (u16*)(ws + 17039360);
    u16* Qb  = (u16*)(ws + 17170432);
    u16* Kb  = (u16*)(ws + 33947648);
    u16* Vtb = (u16*)(ws + 50724864);

    cast_kernel<<<2048, 256, 0, stream>>>(x,  xb,  1048576);
    cast_kernel<<<64,   256, 0, stream>>>(Wq, wqb, 8192);
    cast_kernel<<<64,   256, 0, stream>>>(Wk, wkb, 8192);
    cast_kernel<<<64,   256, 0, stream>>>(Wv, wvb, 8192);

    proj_qk_kernel<<<dim3(4, 256), 256, 0, stream>>>(xb, wqb, wkb, bq, bk, Qb, Kb);
    proj_v_kernel<<<dim3(256, 2), 256, 0, stream>>>(wvb, xb, bv, Vtb);

    attn_kernel<<<dim3(16, 16), 256, 0, stream>>>(Qb, Kb, Vtb, out);
}

// Round 4
// 176.604 us; speedup vs baseline: 1.5613x; 1.1132x over previous
//
#include <hip/hip_runtime.h>
#include <hip/hip_bf16.h>
#include <stdint.h>

#define DEV __device__ __forceinline__

typedef __attribute__((ext_vector_type(8))) short bf16x8;
typedef __attribute__((ext_vector_type(4))) float f32x4;
typedef unsigned short u16;

// ---- async global->LDS, 16B per lane. lds dest must be wave-uniform base. ----
DEV void gload_lds16(const void* g, void* l) {
    typedef const __attribute__((address_space(1))) unsigned int* gp_t;
    typedef __attribute__((address_space(3))) unsigned int* lp_t;
    __builtin_amdgcn_global_load_lds((gp_t)(uintptr_t)g, (lp_t)(uint32_t)(uintptr_t)l, 16, 0, 0);
}

DEV u16 f2bf(float x) {
    union { __hip_bfloat16 h; u16 u; } c;
    c.h = __float2bfloat16(x);
    return c.u;
}
DEV unsigned pack2bf(float a, float b) {
    return (unsigned)f2bf(a) | ((unsigned)f2bf(b) << 16);
}

// ============================ cast fp32 -> bf16 ============================
__global__ void cast_kernel(const float* __restrict__ src, u16* __restrict__ dst, int n8) {
    int stride = gridDim.x * blockDim.x;
    for (int i = blockIdx.x * blockDim.x + threadIdx.x; i < n8; i += stride) {
        const float4* s = (const float4*)src + (size_t)i * 2;
        float4 a = s[0], b = s[1];
        union { u16 u[8]; uint4 v; } o;
        o.u[0] = f2bf(a.x); o.u[1] = f2bf(a.y); o.u[2] = f2bf(a.z); o.u[3] = f2bf(a.w);
        o.u[4] = f2bf(b.x); o.u[5] = f2bf(b.y); o.u[6] = f2bf(b.z); o.u[7] = f2bf(b.w);
        *((uint4*)dst + i) = o.v;
    }
}

// ============================ projection GEMM ==============================
DEV void gemm_body(const u16* A, const u16* Bw, const float* bias, int bias_row,
                   u16* out, int out_pitch)
{
    __shared__ char smA[16384];
    __shared__ char smB[16384];
    const int lane = threadIdx.x & 63;
    const int w    = threadIdx.x >> 6;
    const int wr   = w >> 1, wc = w & 1;
    const int l15  = lane & 15, lg = lane >> 4;

    f32x4 acc[4][4] = {};
    const char* ag = (const char*)A;
    const char* bg = (const char*)Bw;

    for (int kt = 0; kt < 4; ++kt) {
        __syncthreads();
        #pragma unroll
        for (int c = 0; c < 8; ++c) {
            int ch    = w * 8 + c;
            int loc   = ch & 15;
            int p     = loc * 1024 + lane * 16;
            int row   = p >> 7;
            int inner = (p & 127) ^ ((row & 7) << 4);
            const char* src = (ch < 16 ? ag : bg) + row * 512 + kt * 128 + inner;
            char* dst = (ch < 16 ? smA : smB) + loc * 1024;
            gload_lds16(src, dst);
        }
        __syncthreads();
        #pragma unroll
        for (int ks = 0; ks < 2; ++ks) {
            bf16x8 af[4], bfr[4];
            #pragma unroll
            for (int mi = 0; mi < 4; ++mi) {
                int row = wr * 64 + mi * 16 + l15;
                af[mi] = *(const bf16x8*)(smA + ((row * 128 + ks * 64 + lg * 16) ^ ((row & 7) << 4)));
            }
            #pragma unroll
            for (int ni = 0; ni < 4; ++ni) {
                int row = wc * 64 + ni * 16 + l15;
                bfr[ni] = *(const bf16x8*)(smB + ((row * 128 + ks * 64 + lg * 16) ^ ((row & 7) << 4)));
            }
            #pragma unroll
            for (int mi = 0; mi < 4; ++mi)
                #pragma unroll
                for (int ni = 0; ni < 4; ++ni)
                    acc[mi][ni] = __builtin_amdgcn_mfma_f32_16x16x32_bf16(af[mi], bfr[ni], acc[mi][ni], 0, 0, 0);
        }
    }
    #pragma unroll
    for (int mi = 0; mi < 4; ++mi) {
        #pragma unroll
        for (int ni = 0; ni < 4; ++ni) {
            int n_l  = wc * 64 + ni * 16 + l15;
            float bn = bias_row ? 0.f : bias[n_l];
            #pragma unroll
            for (int r = 0; r < 4; ++r) {
                int row  = wr * 64 + mi * 16 + lg * 4 + r;
                float bb = bias_row ? bias[row] : bn;
                out[(size_t)row * out_pitch + n_l] = f2bf(acc[mi][ni][r] + bb);
            }
        }
    }
}

__global__ __launch_bounds__(256) void proj_qk_kernel(
    const u16* xb, const u16* wqb, const u16* wkb,
    const float* bq, const float* bk, u16* Q, u16* K)
{
    int n0 = blockIdx.x * 128;
    int m0 = blockIdx.y * 128;
    bool isK = n0 >= 256;
    int  nl  = n0 & 255;
    gemm_body(xb + (size_t)m0 * 256, (isK ? wkb : wqb) + (size_t)nl * 256,
              (isK ? bk : bq) + nl, 0,
              (isK ? K : Q) + (size_t)m0 * 256 + nl, 256);
}

__global__ __launch_bounds__(256) void proj_v_kernel(
    const u16* wvb, const u16* xb, const float* bv, u16* Vt)
{
    int n0 = blockIdx.x * 128;
    int m0 = blockIdx.y * 128;
    gemm_body(wvb + (size_t)m0 * 256, xb + (size_t)n0 * 256, bv + m0, 1,
              Vt + (size_t)m0 * 32768 + n0, 32768);
}

// ============================ fused attention ==============================
// 16x16x32 MFMA path: 4 waves x 16 q-rows = 64 q/block, grid 512 = 2 blocks/CU
// (2 waves/SIMD from independent blocks -> barrier drains overlap with the
// partner block's compute). KVBLK=32 double-buffered, 64KB LDS.
// Lane roles: l15 = lane&15 (q column), lg = lane>>4 (k-slice group).
// S^T = K*Q^T per 16-kv tile mt: lane owns S[q=l15][kv=mt*16+lg*4+r].
__global__ __launch_bounds__(256, 2) void attn_kernel(
    const u16* __restrict__ Q, const u16* __restrict__ K,
    const u16* __restrict__ Vt, float* __restrict__ out)
{
    __shared__ char sm[65536];
    // K tile t: sm + (t&1)*16384:        [32 kv][512B], swz byte ^= (row&7)<<4
    // V tile t: sm + 32768 + (t&1)*16384: [256 d][64B], swz byte ^= ((row>>1)&3)<<4

    const int lane = threadIdx.x & 63;
    const int w    = threadIdx.x >> 6;
    const int l15  = lane & 15;
    const int lg   = lane >> 4;

    // XCD batch-confinement: XCD (lin%8) serves 2 batches -> K/V (4MB) L2-resident
    const int lin = blockIdx.y * 32 + blockIdx.x;
    const int b   = (lin & 7) * 2 + ((lin >> 3) & 1);
    const int qt  = lin >> 4;                     // 0..31
    const size_t tokbase = (size_t)b * 2048;
    const int q0w = qt * 64 + w * 16;             // this wave's 16 q-rows

    // Q fragments (B-operand): lane holds Q[q0w+l15][ks*32 + lg*8 + j]
    bf16x8 qf[8];
    {
        const char* qrow = (const char*)(Q + (tokbase + q0w + l15) * 256);
        #pragma unroll
        for (int ks = 0; ks < 8; ++ks)
            qf[ks] = *(const bf16x8*)(qrow + ks * 64 + lg * 16);
    }

    // staging: waves 0,1 -> K tile (16x1KB chunks), waves 2,3 -> V tile
    auto stage = [&](int t) {
        const int kv0 = t * 32;
        char* kb = sm + ((t & 1) << 14);
        char* vb = sm + 32768 + ((t & 1) << 14);
        if (w < 2) {
            #pragma unroll
            for (int c = 0; c < 8; ++c) {
                int ch    = w * 8 + c;
                int row   = ch * 2 + (lane >> 5);
                int inner = ((lane & 31) * 16) ^ ((row & 7) << 4);
                gload_lds16((const char*)K + (tokbase + kv0 + row) * 512 + inner,
                            kb + ch * 1024);
            }
        } else {
            #pragma unroll
            for (int c = 0; c < 8; ++c) {
                int ch    = (w - 2) * 8 + c;
                int row   = ch * 16 + (lane >> 2);
                int inner = ((lane & 3) * 16) ^ (((row >> 1) & 3) << 4);
                gload_lds16((const char*)Vt + (size_t)row * 65536 + (size_t)(tokbase + kv0) * 2 + inner,
                            vb + ch * 1024);
            }
        }
    };

    f32x4 acc[16] = {};     // O^T: acc[dt][r] = O[d=dt*16+lg*4+r][q=l15]
    float m_run = -1e30f;
    float l_run = 0.f;
    const float C = 0.09016844005556021f;   // (1/16)*log2(e)

    stage(0);
    __syncthreads();

    for (int kt = 0; kt < 64; ++kt) {
        const char* kls = sm + ((kt & 1) << 14);
        const char* vls = sm + 32768 + ((kt & 1) << 14);

        // ---- S^T = K * Q^T (two 16-kv tiles, K-dim 256 = 8 slices)
        f32x4 st0 = {}, st1 = {};
        #pragma unroll
        for (int ks = 0; ks < 8; ++ks) {
            int r0 = l15, r1 = 16 + l15;
            bf16x8 kf0 = *(const bf16x8*)(kls + ((r0 * 512 + ks * 64 + lg * 16) ^ ((r0 & 7) << 4)));
            bf16x8 kf1 = *(const bf16x8*)(kls + ((r1 * 512 + ks * 64 + lg * 16) ^ ((r1 & 7) << 4)));
            st0 = __builtin_amdgcn_mfma_f32_16x16x32_bf16(kf0, qf[ks], st0, 0, 0, 0);
            st1 = __builtin_amdgcn_mfma_f32_16x16x32_bf16(kf1, qf[ks], st1, 0, 0, 0);
        }

        // ---- online softmax: q-row group = 4 lanes {l15, l15^16, l15^32, l15^48}
        float p0 = fmaxf(fmaxf(st0[0], st0[1]), fmaxf(st0[2], st0[3]));
        float p1 = fmaxf(fmaxf(st1[0], st1[1]), fmaxf(st1[2], st1[3]));
        float pmax = fmaxf(p0, p1);
        pmax = fmaxf(pmax, __shfl_xor(pmax, 16, 64));
        pmax = fmaxf(pmax, __shfl_xor(pmax, 32, 64));

        bool upd = pmax > m_run + 16.f;     // defer-max (raw units; *C bounds exp arg)
        if (__any(upd)) {
            float m_new = upd ? pmax : m_run;
            float rs = upd ? exp2f((m_run - m_new) * C) : 1.f;
            #pragma unroll
            for (int dt = 0; dt < 16; ++dt) acc[dt] *= rs;
            l_run *= rs;
            m_run = m_new;
        }

        const float mc = m_run * C;
        float sum = 0.f;
        #pragma unroll
        for (int i = 0; i < 4; ++i) {
            float e0 = exp2f(st0[i] * C - mc);
            float e1 = exp2f(st1[i] * C - mc);
            st0[i] = e0; st1[i] = e1;
            sum += e0 + e1;
        }
        sum += __shfl_xor(sum, 16, 64);
        sum += __shfl_xor(sum, 32, 64);
        l_run += sum;

        // ---- pack own P dwords: dM_h = kv pair {M*16+lg*4+2h, +1} at q=l15
        unsigned d00 = pack2bf(st0[0], st0[1]);
        unsigned d01 = pack2bf(st0[2], st0[3]);
        unsigned d10 = pack2bf(st1[0], st1[1]);
        unsigned d11 = pack2bf(st1[2], st1[3]);

        // ---- exchange to PV B-frag: lane needs P[q=l15][kv=lg*8 .. lg*8+7]
        // round m: contribution = D[((lg^(m>>4))>>1)&1]
        unsigned own0 = (lg & 2) ? d10 : d00;   // D[lg>>1][0]
        unsigned own1 = (lg & 2) ? d11 : d01;
        unsigned cx0  = (lg & 2) ? d00 : d10;   // D[(lg>>1)^1][0]
        unsigned cx1  = (lg & 2) ? d01 : d11;
        unsigned r16_0 = __shfl_xor(own0, 16, 64);
        unsigned r16_1 = __shfl_xor(own1, 16, 64);
        unsigned r32_0 = __shfl_xor(cx0, 32, 64);
        unsigned r32_1 = __shfl_xor(cx1, 32, 64);
        unsigned r48_0 = __shfl_xor(cx0, 48, 64);
        unsigned r48_1 = __shfl_xor(cx1, 48, 64);
        union { unsigned u[4]; bf16x8 v; } pf;
        pf.u[0] = (lg == 0) ? own0 : (lg == 1) ? r48_0 : (lg == 2) ? r32_0 : r16_0;
        pf.u[1] = (lg == 0) ? own1 : (lg == 1) ? r48_1 : (lg == 2) ? r32_1 : r16_1;
        pf.u[2] = (lg == 0) ? r16_0 : (lg == 1) ? r32_0 : (lg == 2) ? r48_0 : own0;
        pf.u[3] = (lg == 0) ? r16_1 : (lg == 1) ? r32_1 : (lg == 2) ? r48_1 : own1;

        // ---- PV: acc[dt] += Vt_tile(dt) * P^T   (A row = d, k = kv = lg*8+j)
        #pragma unroll
        for (int dt = 0; dt < 16; ++dt) {
            int row = dt * 16 + l15;
            bf16x8 vf = *(const bf16x8*)(vls + ((row * 64 + lg * 16) ^ (((row >> 1) & 3) << 4)));
            acc[dt] = __builtin_amdgcn_mfma_f32_16x16x32_bf16(vf, pf.v, acc[dt], 0, 0, 0);
        }

        if (kt < 63) stage(kt + 1);   // issue after all LDS reads; drained at barrier
        __syncthreads();
    }

    // ---- epilogue: O = acc / l_run; transpose 64-d chunks via per-wave LDS
    const float inv = 1.f / l_run;
    float* ow = (float*)(sm + w * 4352);   // [16 q][68 f32]
    #pragma unroll
    for (int p = 0; p < 4; ++p) {
        #pragma unroll
        for (int d2 = 0; d2 < 4; ++d2) {
            const int dt = p * 4 + d2;
            #pragma unroll
            for (int r = 0; r < 4; ++r)
                ow[l15 * 68 + d2 * 16 + lg * 4 + r] = acc[dt][r] * inv;
        }
        const int row = lane >> 2;
        const int c0  = (lane & 3) * 16;
        #pragma unroll
        for (int i = 0; i < 4; ++i) {
            float4 v = *(const float4*)(ow + row * 68 + c0 + i * 4);
            *(float4*)(out + (tokbase + q0w + row) * 256 + p * 64 + c0 + i * 4) = v;
        }
    }
}

// ================================ launch ===================================
extern "C" void kernel_launch(void* const* d_in, const int* in_sizes, int n_in,
                              void* d_out, int out_size, void* d_ws, size_t ws_size,
                              hipStream_t stream) {
    (void)in_sizes; (void)n_in; (void)out_size; (void)ws_size;
    const float* x  = (const float*)d_in[0];
    const float* Wq = (const float*)d_in[1];
    const float* bq = (const float*)d_in[2];
    const float* Wk = (const float*)d_in[3];
    const float* bk = (const float*)d_in[4];
    const float* Wv = (const float*)d_in[5];
    const float* bv = (const float*)d_in[6];
    float* out = (float*)d_out;

    char* ws = (char*)d_ws;
    u16* xb  = (u16*)(ws);
    u16* wqb = (u16*)(ws + 16777216);
    u16* wkb = (u16*)(ws + 16908288);
    u16* wvb = (u16*)(ws + 17039360);
    u16* Qb  = (u16*)(ws + 17170432);
    u16* Kb  = (u16*)(ws + 33947648);
    u16* Vtb = (u16*)(ws + 50724864);

    cast_kernel<<<2048, 256, 0, stream>>>(x,  xb,  1048576);
    cast_kernel<<<64,   256, 0, stream>>>(Wq, wqb, 8192);
    cast_kernel<<<64,   256, 0, stream>>>(Wk, wkb, 8192);
    cast_kernel<<<64,   256, 0, stream>>>(Wv, wvb, 8192);

    proj_qk_kernel<<<dim3(4, 256), 256, 0, stream>>>(xb, wqb, wkb, bq, bk, Qb, Kb);
    proj_v_kernel<<<dim3(256, 2), 256, 0, stream>>>(wvb, xb, bv, Vtb);

    attn_kernel<<<dim3(32, 16), 256, 0, stream>>>(Qb, Kb, Vtb, out);
}

// Round 5
// 166.274 us; speedup vs baseline: 1.6583x; 1.0621x over previous
//
#include <hip/hip_runtime.h>
#include <hip/hip_bf16.h>
#include <stdint.h>

#define DEV __device__ __forceinline__

typedef __attribute__((ext_vector_type(8))) short bf16x8;
typedef __attribute__((ext_vector_type(4))) float f32x4;
typedef unsigned short u16;

// ---- async global->LDS, 16B per lane. lds dest must be wave-uniform base. ----
DEV void gload_lds16(const void* g, void* l) {
    typedef const __attribute__((address_space(1))) unsigned int* gp_t;
    typedef __attribute__((address_space(3))) unsigned int* lp_t;
    __builtin_amdgcn_global_load_lds((gp_t)(uintptr_t)g, (lp_t)(uint32_t)(uintptr_t)l, 16, 0, 0);
}

DEV u16 f2bf(float x) {
    union { __hip_bfloat16 h; u16 u; } c;
    c.h = __float2bfloat16(x);
    return c.u;
}
DEV unsigned pack2bf(float a, float b) {
    return (unsigned)f2bf(a) | ((unsigned)f2bf(b) << 16);
}

// ============================ cast fp32 -> bf16 ============================
__global__ void cast_kernel(const float* __restrict__ src, u16* __restrict__ dst, int n8) {
    int stride = gridDim.x * blockDim.x;
    for (int i = blockIdx.x * blockDim.x + threadIdx.x; i < n8; i += stride) {
        const float4* s = (const float4*)src + (size_t)i * 2;
        float4 a = s[0], b = s[1];
        union { u16 u[8]; uint4 v; } o;
        o.u[0] = f2bf(a.x); o.u[1] = f2bf(a.y); o.u[2] = f2bf(a.z); o.u[3] = f2bf(a.w);
        o.u[4] = f2bf(b.x); o.u[5] = f2bf(b.y); o.u[6] = f2bf(b.z); o.u[7] = f2bf(b.w);
        *((uint4*)dst + i) = o.v;
    }
}

// ============================ projection GEMM ==============================
DEV void gemm_body(const u16* A, const u16* Bw, const float* bias, int bias_row,
                   u16* out, int out_pitch)
{
    __shared__ char smA[16384];
    __shared__ char smB[16384];
    const int lane = threadIdx.x & 63;
    const int w    = threadIdx.x >> 6;
    const int wr   = w >> 1, wc = w & 1;
    const int l15  = lane & 15, lg = lane >> 4;

    f32x4 acc[4][4] = {};
    const char* ag = (const char*)A;
    const char* bg = (const char*)Bw;

    for (int kt = 0; kt < 4; ++kt) {
        __syncthreads();
        #pragma unroll
        for (int c = 0; c < 8; ++c) {
            int ch    = w * 8 + c;
            int loc   = ch & 15;
            int p     = loc * 1024 + lane * 16;
            int row   = p >> 7;
            int inner = (p & 127) ^ ((row & 7) << 4);
            const char* src = (ch < 16 ? ag : bg) + row * 512 + kt * 128 + inner;
            char* dst = (ch < 16 ? smA : smB) + loc * 1024;
            gload_lds16(src, dst);
        }
        __syncthreads();
        #pragma unroll
        for (int ks = 0; ks < 2; ++ks) {
            bf16x8 af[4], bfr[4];
            #pragma unroll
            for (int mi = 0; mi < 4; ++mi) {
                int row = wr * 64 + mi * 16 + l15;
                af[mi] = *(const bf16x8*)(smA + ((row * 128 + ks * 64 + lg * 16) ^ ((row & 7) << 4)));
            }
            #pragma unroll
            for (int ni = 0; ni < 4; ++ni) {
                int row = wc * 64 + ni * 16 + l15;
                bfr[ni] = *(const bf16x8*)(smB + ((row * 128 + ks * 64 + lg * 16) ^ ((row & 7) << 4)));
            }
            #pragma unroll
            for (int mi = 0; mi < 4; ++mi)
                #pragma unroll
                for (int ni = 0; ni < 4; ++ni)
                    acc[mi][ni] = __builtin_amdgcn_mfma_f32_16x16x32_bf16(af[mi], bfr[ni], acc[mi][ni], 0, 0, 0);
        }
    }
    #pragma unroll
    for (int mi = 0; mi < 4; ++mi) {
        #pragma unroll
        for (int ni = 0; ni < 4; ++ni) {
            int n_l  = wc * 64 + ni * 16 + l15;
            float bn = bias_row ? 0.f : bias[n_l];
            #pragma unroll
            for (int r = 0; r < 4; ++r) {
                int row  = wr * 64 + mi * 16 + lg * 4 + r;
                float bb = bias_row ? bias[row] : bn;
                out[(size_t)row * out_pitch + n_l] = f2bf(acc[mi][ni][r] + bb);
            }
        }
    }
}

__global__ __launch_bounds__(256) void proj_qk_kernel(
    const u16* xb, const u16* wqb, const u16* wkb,
    const float* bq, const float* bk, u16* Q, u16* K)
{
    int n0 = blockIdx.x * 128;
    int m0 = blockIdx.y * 128;
    bool isK = n0 >= 256;
    int  nl  = n0 & 255;
    gemm_body(xb + (size_t)m0 * 256, (isK ? wkb : wqb) + (size_t)nl * 256,
              (isK ? bk : bq) + nl, 0,
              (isK ? K : Q) + (size_t)m0 * 256 + nl, 256);
}

__global__ __launch_bounds__(256) void proj_v_kernel(
    const u16* wvb, const u16* xb, const float* bv, u16* Vt)
{
    int n0 = blockIdx.x * 128;
    int m0 = blockIdx.y * 128;
    gemm_body(wvb + (size_t)m0 * 256, xb + (size_t)n0 * 256, bv + m0, 1,
              Vt + (size_t)m0 * 32768 + n0, 32768);
}

// ============================ fused attention ==============================
// 4 waves x 16 q-rows = 64 q/block, grid 512 = 2 blocks/CU (2 waves/SIMD from
// independent blocks). KVBLK=32 double-buffered, 64KB LDS.
// Schedule per tile: [barrier from prev iter] -> stage(kt+1) -> compute(kt)
// -> __syncthreads(). Stage loads get the whole compute phase in flight before
// the barrier's vmcnt(0) drain. Softmax fast path has ZERO cross-lane shuffles
// (lazy max check; l-reduction deferred to epilogue).
__global__ __launch_bounds__(256, 2) void attn_kernel(
    const u16* __restrict__ Q, const u16* __restrict__ K,
    const u16* __restrict__ Vt, float* __restrict__ out)
{
    __shared__ char sm[65536];
    // K tile t: sm + (t&1)*16384:        [32 kv][512B], swz byte ^= (row&7)<<4
    // V tile t: sm + 32768 + (t&1)*16384: [256 d][64B], swz byte ^= ((row>>1)&3)<<4

    const int lane = threadIdx.x & 63;
    const int w    = threadIdx.x >> 6;
    const int l15  = lane & 15;
    const int lg   = lane >> 4;

    // XCD batch-confinement: XCD (lin%8) serves 2 batches -> K/V (4MB) L2-resident
    const int lin = blockIdx.y * 32 + blockIdx.x;
    const int b   = (lin & 7) * 2 + ((lin >> 3) & 1);
    const int qt  = lin >> 4;                     // 0..31
    const size_t tokbase = (size_t)b * 2048;
    const int q0w = qt * 64 + w * 16;             // this wave's 16 q-rows

    // Q fragments (B-operand): lane holds Q[q0w+l15][ks*32 + lg*8 + j]
    bf16x8 qf[8];
    {
        const char* qrow = (const char*)(Q + (tokbase + q0w + l15) * 256);
        #pragma unroll
        for (int ks = 0; ks < 8; ++ks)
            qf[ks] = *(const bf16x8*)(qrow + ks * 64 + lg * 16);
    }

    // staging: waves 0,1 -> K tile (16x1KB chunks), waves 2,3 -> V tile
    auto stage = [&](int t) {
        const int kv0 = t * 32;
        char* kb = sm + ((t & 1) << 14);
        char* vb = sm + 32768 + ((t & 1) << 14);
        if (w < 2) {
            #pragma unroll
            for (int c = 0; c < 8; ++c) {
                int ch    = w * 8 + c;
                int row   = ch * 2 + (lane >> 5);
                int inner = ((lane & 31) * 16) ^ ((row & 7) << 4);
                gload_lds16((const char*)K + (tokbase + kv0 + row) * 512 + inner,
                            kb + ch * 1024);
            }
        } else {
            #pragma unroll
            for (int c = 0; c < 8; ++c) {
                int ch    = (w - 2) * 8 + c;
                int row   = ch * 16 + (lane >> 2);
                int inner = ((lane & 3) * 16) ^ (((row >> 1) & 3) << 4);
                gload_lds16((const char*)Vt + (size_t)row * 65536 + (size_t)(tokbase + kv0) * 2 + inner,
                            vb + ch * 1024);
            }
        }
    };

    f32x4 acc[16] = {};     // O^T: acc[dt][r] = O[d=dt*16+lg*4+r][q=l15]
    float m_run = -1e30f;
    float l_lane = 0.f;     // per-lane partial denominator; reduced in epilogue
    const float C = 0.09016844005556021f;   // (1/16)*log2(e)

    stage(0);
    __syncthreads();

    for (int kt = 0; kt < 64; ++kt) {
        if (kt < 63) stage(kt + 1);   // issue first: full compute phase in flight

        const char* kls = sm + ((kt & 1) << 14);
        const char* vls = sm + 32768 + ((kt & 1) << 14);

        // ---- S^T = K * Q^T (two 16-kv tiles, K-dim 256 = 8 slices)
        f32x4 st0 = {}, st1 = {};
        #pragma unroll
        for (int ks = 0; ks < 8; ++ks) {
            int r0 = l15, r1 = 16 + l15;
            bf16x8 kf0 = *(const bf16x8*)(kls + ((r0 * 512 + ks * 64 + lg * 16) ^ ((r0 & 7) << 4)));
            bf16x8 kf1 = *(const bf16x8*)(kls + ((r1 * 512 + ks * 64 + lg * 16) ^ ((r1 & 7) << 4)));
            st0 = __builtin_amdgcn_mfma_f32_16x16x32_bf16(kf0, qf[ks], st0, 0, 0, 0);
            st1 = __builtin_amdgcn_mfma_f32_16x16x32_bf16(kf1, qf[ks], st1, 0, 0, 0);
        }

        // ---- online softmax, shuffle-free fast path.
        // lane-local max over this lane's 8 kv values; row max only if tripped.
        float p0 = fmaxf(fmaxf(st0[0], st0[1]), fmaxf(st0[2], st0[3]));
        float p1 = fmaxf(fmaxf(st1[0], st1[1]), fmaxf(st1[2], st1[3]));
        float lmax = fmaxf(p0, p1);

        if (__any(lmax > m_run + 16.f)) {   // rare after tile 0
            float rmax = lmax;
            rmax = fmaxf(rmax, __shfl_xor(rmax, 16, 64));
            rmax = fmaxf(rmax, __shfl_xor(rmax, 32, 64));   // row-consistent
            float m_new = fmaxf(m_run, rmax);
            float rs = exp2f((m_run - m_new) * C);
            #pragma unroll
            for (int dt = 0; dt < 16; ++dt) acc[dt] *= rs;
            l_lane *= rs;
            m_run = m_new;
        }
        // P = exp2((S - m_run)*C) bounded by exp2(16*C) = e (bf16-safe)

        const float mc = m_run * C;
        float sum = 0.f;
        #pragma unroll
        for (int i = 0; i < 4; ++i) {
            float e0 = exp2f(st0[i] * C - mc);
            float e1 = exp2f(st1[i] * C - mc);
            st0[i] = e0; st1[i] = e1;
            sum += e0 + e1;
        }
        l_lane += sum;       // per-lane partial; no shuffle here

        // ---- pack own P dwords: dM_h = kv pair {M*16+lg*4+2h, +1} at q=l15
        unsigned d00 = pack2bf(st0[0], st0[1]);
        unsigned d01 = pack2bf(st0[2], st0[3]);
        unsigned d10 = pack2bf(st1[0], st1[1]);
        unsigned d11 = pack2bf(st1[2], st1[3]);

        // ---- exchange to PV B-frag: lane needs P[q=l15][kv=lg*8 .. lg*8+7]
        unsigned own0 = (lg & 2) ? d10 : d00;   // D[lg>>1][0]
        unsigned own1 = (lg & 2) ? d11 : d01;
        unsigned cx0  = (lg & 2) ? d00 : d10;   // D[(lg>>1)^1][0]
        unsigned cx1  = (lg & 2) ? d01 : d11;
        unsigned r16_0 = __shfl_xor(own0, 16, 64);
        unsigned r16_1 = __shfl_xor(own1, 16, 64);
        unsigned r32_0 = __shfl_xor(cx0, 32, 64);
        unsigned r32_1 = __shfl_xor(cx1, 32, 64);
        unsigned r48_0 = __shfl_xor(cx0, 48, 64);
        unsigned r48_1 = __shfl_xor(cx1, 48, 64);
        union { unsigned u[4]; bf16x8 v; } pf;
        pf.u[0] = (lg == 0) ? own0 : (lg == 1) ? r48_0 : (lg == 2) ? r32_0 : r16_0;
        pf.u[1] = (lg == 0) ? own1 : (lg == 1) ? r48_1 : (lg == 2) ? r32_1 : r16_1;
        pf.u[2] = (lg == 0) ? r16_0 : (lg == 1) ? r32_0 : (lg == 2) ? r48_0 : own0;
        pf.u[3] = (lg == 0) ? r16_1 : (lg == 1) ? r32_1 : (lg == 2) ? r48_1 : own1;

        // ---- PV: acc[dt] += Vt_tile(dt) * P^T   (A row = d, k = kv = lg*8+j)
        #pragma unroll
        for (int dt = 0; dt < 16; ++dt) {
            int row = dt * 16 + l15;
            bf16x8 vf = *(const bf16x8*)(vls + ((row * 64 + lg * 16) ^ (((row >> 1) & 3) << 4)));
            acc[dt] = __builtin_amdgcn_mfma_f32_16x16x32_bf16(vf, pf.v, acc[dt], 0, 0, 0);
        }

        __syncthreads();   // stage loads have been in flight for the whole iter
    }

    // ---- deferred denominator reduce (row = lanes {l15, ^16, ^32, ^48})
    float l_row = l_lane;
    l_row += __shfl_xor(l_row, 16, 64);
    l_row += __shfl_xor(l_row, 32, 64);
    const float inv = 1.f / l_row;

    // ---- epilogue: O = acc * inv; transpose 64-d chunks via per-wave LDS
    float* ow = (float*)(sm + w * 4352);   // [16 q][68 f32]
    #pragma unroll
    for (int p = 0; p < 4; ++p) {
        #pragma unroll
        for (int d2 = 0; d2 < 4; ++d2) {
            const int dt = p * 4 + d2;
            #pragma unroll
            for (int r = 0; r < 4; ++r)
                ow[l15 * 68 + d2 * 16 + lg * 4 + r] = acc[dt][r] * inv;
        }
        const int row = lane >> 2;
        const int c0  = (lane & 3) * 16;
        #pragma unroll
        for (int i = 0; i < 4; ++i) {
            float4 v = *(const float4*)(ow + row * 68 + c0 + i * 4);
            *(float4*)(out + (tokbase + q0w + row) * 256 + p * 64 + c0 + i * 4) = v;
        }
    }
}

// ================================ launch ===================================
extern "C" void kernel_launch(void* const* d_in, const int* in_sizes, int n_in,
                              void* d_out, int out_size, void* d_ws, size_t ws_size,
                              hipStream_t stream) {
    (void)in_sizes; (void)n_in; (void)out_size; (void)ws_size;
    const float* x  = (const float*)d_in[0];
    const float* Wq = (const float*)d_in[1];
    const float* bq = (const float*)d_in[2];
    const float* Wk = (const float*)d_in[3];
    const float* bk = (const float*)d_in[4];
    const float* Wv = (const float*)d_in[5];
    const float* bv = (const float*)d_in[6];
    float* out = (float*)d_out;

    char* ws = (char*)d_ws;
    u16* xb  = (u16*)(ws);
    u16* wqb = (u16*)(ws + 16777216);
    u16* wkb = (u16*)(ws + 16908288);
    u16* wvb = (u16*)(ws + 17039360);
    u16* Qb  = (u16*)(ws + 17170432);
    u16* Kb  = (u16*)(ws + 33947648);
    u16* Vtb = (u16*)(ws + 50724864);

    cast_kernel<<<2048, 256, 0, stream>>>(x,  xb,  1048576);
    cast_kernel<<<64,   256, 0, stream>>>(Wq, wqb, 8192);
    cast_kernel<<<64,   256, 0, stream>>>(Wk, wkb, 8192);
    cast_kernel<<<64,   256, 0, stream>>>(Wv, wvb, 8192);

    proj_qk_kernel<<<dim3(4, 256), 256, 0, stream>>>(xb, wqb, wkb, bq, bk, Qb, Kb);
    proj_v_kernel<<<dim3(256, 2), 256, 0, stream>>>(wvb, xb, bv, Vtb);

    attn_kernel<<<dim3(32, 16), 256, 0, stream>>>(Qb, Kb, Vtb, out);
}